// Round 5
// baseline (582.913 us; speedup 1.0000x reference)
//
#include <hip/hip_runtime.h>

#define DK 256    // K dim of every GEMM (D_IN == D_HID == 256)
#define BN 256    // nodes per CSR bucket (dst >> 8)
#define NBLK 512  // partition blocks for hist/part

typedef __attribute__((ext_vector_type(8))) short bf16x8;   // 8 bf16 in 4 VGPRs
typedef __attribute__((ext_vector_type(4))) float f32x4;
typedef __attribute__((ext_vector_type(2))) float f32x2;
typedef __attribute__((ext_vector_type(4))) unsigned short u16x4;

__device__ __forceinline__ unsigned short f2b(float f) {    // RNE fp32->bf16
    unsigned u = __builtin_bit_cast(unsigned, f);
    u += 0x7FFFu + ((u >> 16) & 1u);
    return (unsigned short)(u >> 16);
}
__device__ __forceinline__ float b2f(unsigned short s) {
    return __builtin_bit_cast(float, (unsigned)s << 16);
}
__device__ __forceinline__ void gld_lds16(void* lds, const void* g) {
    __builtin_amdgcn_global_load_lds(
        (const __attribute__((address_space(1))) unsigned int*)g,
        (__attribute__((address_space(3))) unsigned int*)lds, 16, 0, 0);
}

// ---------------------------------------------------------------------------
// fp32 -> bf16 conversion, 4 elems/thread (src streamed nt; dst allocating)
// ---------------------------------------------------------------------------
__global__ __launch_bounds__(256) void k_cvt(const float* __restrict__ src,
                                             unsigned short* __restrict__ dst, int n4) {
    int i = blockIdx.x * 256 + threadIdx.x;
    if (i < n4) {
        f32x4 v = __builtin_nontemporal_load(reinterpret_cast<const f32x4*>(src) + i);
        ushort4 o = make_ushort4(f2b(v.x), f2b(v.y), f2b(v.z), f2b(v.w));
        reinterpret_cast<ushort4*>(dst)[i] = o;
    }
}

// ---------------------------------------------------------------------------
// generic 3-kernel exclusive scan (1024 elems per scan_a/scan_c block)
// ---------------------------------------------------------------------------
__global__ __launch_bounds__(256) void k_scan_a(const int* __restrict__ in,
                                                int* __restrict__ bsum, int N) {
    __shared__ int sm[256];
    int t = threadIdx.x;
    int i0 = blockIdx.x * 1024 + t * 4;
    int s = 0;
    if (i0 + 3 < N) {
        int4 v = *reinterpret_cast<const int4*>(in + i0);
        s = v.x + v.y + v.z + v.w;
    } else {
        for (int i = i0; i < min(i0 + 4, N); ++i) s += in[i];
    }
    sm[t] = s;
    __syncthreads();
    for (int off = 128; off > 0; off >>= 1) {
        if (t < off) sm[t] += sm[t + off];
        __syncthreads();
    }
    if (t == 0) bsum[blockIdx.x] = sm[0];
}

__global__ __launch_bounds__(256) void k_scan_b(const int* __restrict__ bsum,
                                                int* __restrict__ boff,
                                                int* __restrict__ totN, int NB) {
    __shared__ int sm[256];
    int t = threadIdx.x;
    sm[t] = (t < NB) ? bsum[t] : 0;
    __syncthreads();
    for (int off = 1; off < 256; off <<= 1) {
        int v = (t >= off) ? sm[t - off] : 0;
        __syncthreads();
        sm[t] += v;
        __syncthreads();
    }
    if (t < NB) boff[t] = (t == 0) ? 0 : sm[t - 1];
    if (t == NB - 1) *totN = sm[t];
}

// exclusive-scan writeback + rowptr/invdeg epilogue (for degi scan)
__global__ __launch_bounds__(256) void k_scan_c(const int* __restrict__ in,
                                                const int* __restrict__ boff,
                                                int* __restrict__ rowptr,
                                                float* __restrict__ invdeg, int N) {
    __shared__ int sm[256];
    int t = threadIdx.x;
    int i0 = blockIdx.x * 1024 + t * 4;
    int d0 = 0, d1 = 0, d2 = 0, d3 = 0;
    if (i0 + 3 < N) {
        int4 v = *reinterpret_cast<const int4*>(in + i0);
        d0 = v.x; d1 = v.y; d2 = v.z; d3 = v.w;
    } else {
        if (i0 + 0 < N) d0 = in[i0 + 0];
        if (i0 + 1 < N) d1 = in[i0 + 1];
        if (i0 + 2 < N) d2 = in[i0 + 2];
        if (i0 + 3 < N) d3 = in[i0 + 3];
    }
    int s = d0 + d1 + d2 + d3;
    sm[t] = s;
    __syncthreads();
    for (int off = 1; off < 256; off <<= 1) {
        int v = (t >= off) ? sm[t - off] : 0;
        __syncthreads();
        sm[t] += v;
        __syncthreads();
    }
    int run = boff[blockIdx.x] + sm[t] - s;    // exclusive prefix of this thread
    int dd[4] = {d0, d1, d2, d3};
#pragma unroll
    for (int i = 0; i < 4; ++i) {
        int idx = i0 + i;
        if (idx < N) {
            rowptr[idx] = run;
            invdeg[idx] = 1.0f / fmaxf((float)dd[i], 1.0f);
            run += dd[i];
        }
    }
}

// exclusive-scan writeback, plain (for histogram scan)
__global__ __launch_bounds__(256) void k_scan_c2(const int* __restrict__ in,
                                                 const int* __restrict__ boff,
                                                 int* __restrict__ outx, int N) {
    __shared__ int sm[256];
    int t = threadIdx.x;
    int i0 = blockIdx.x * 1024 + t * 4;
    int d0 = 0, d1 = 0, d2 = 0, d3 = 0;
    if (i0 + 3 < N) {
        int4 v = *reinterpret_cast<const int4*>(in + i0);
        d0 = v.x; d1 = v.y; d2 = v.z; d3 = v.w;
    } else {
        if (i0 + 0 < N) d0 = in[i0 + 0];
        if (i0 + 1 < N) d1 = in[i0 + 1];
        if (i0 + 2 < N) d2 = in[i0 + 2];
        if (i0 + 3 < N) d3 = in[i0 + 3];
    }
    int s = d0 + d1 + d2 + d3;
    sm[t] = s;
    __syncthreads();
    for (int off = 1; off < 256; off <<= 1) {
        int v = (t >= off) ? sm[t - off] : 0;
        __syncthreads();
        sm[t] += v;
        __syncthreads();
    }
    int run = boff[blockIdx.x] + sm[t] - s;
    int dd[4] = {d0, d1, d2, d3};
#pragma unroll
    for (int i = 0; i < 4; ++i) {
        int idx = i0 + i;
        if (idx < N) { outx[idx] = run; run += dd[i]; }
    }
}

// ---------------------------------------------------------------------------
// CSR build via deterministic counting-sort partition (no global atomics)
// All bulk streams are single-use -> nontemporal (protect L3 for gather srcs)
// ---------------------------------------------------------------------------
// pass A: per-block LDS histogram over NBUK buckets of dst>>8
__global__ __launch_bounds__(256) void k_hist(const int* __restrict__ dst,
                                              int* __restrict__ hist,
                                              int E, int NBUK) {
    extern __shared__ int h[];
    int t = threadIdx.x;
    for (int b = t; b < NBUK; b += 256) h[b] = 0;
    __syncthreads();
    int CH = (E + NBLK - 1) / NBLK;
    int beg = blockIdx.x * CH;
    int end = min(beg + CH, E);
    for (int i = beg + t; i < end; i += 256)
        atomicAdd(&h[__builtin_nontemporal_load(dst + i) >> 8], 1);
    __syncthreads();
    for (int b = t; b < NBUK; b += 256)
        hist[b * NBLK + blockIdx.x] = h[b];     // bucket-major for the scan
}

// pass B: deterministic placement; pack src | (dst&255)<<20 into 4B
__global__ __launch_bounds__(256) void k_part(const int* __restrict__ src,
                                              const int* __restrict__ dst,
                                              const int* __restrict__ hoff,
                                              unsigned* __restrict__ scratch,
                                              int E, int NBUK) {
    extern __shared__ int cur[];
    int t = threadIdx.x;
    for (int b = t; b < NBUK; b += 256) cur[b] = hoff[b * NBLK + blockIdx.x];
    __syncthreads();
    int CH = (E + NBLK - 1) / NBLK;
    int beg = blockIdx.x * CH;
    int end = min(beg + CH, E);
    for (int i = beg + t; i < end; i += 256) {
        int d = __builtin_nontemporal_load(dst + i);
        int s = __builtin_nontemporal_load(src + i);
        int p = atomicAdd(&cur[d >> 8], 1);     // LDS atomic only
        __builtin_nontemporal_store((unsigned)s | ((unsigned)(d & 255) << 20),
                                    scratch + p);
    }
}

// per-bucket degree count from sorted scratch (replaces global-atomic k_deg_i)
__global__ __launch_bounds__(256) void k_degb(const unsigned* __restrict__ scratch,
                                              const int* __restrict__ hoff,
                                              int* __restrict__ degi,
                                              int E, int NBUK, int N) {
    __shared__ int cnt[BN];
    int b = blockIdx.x;
    int t = threadIdx.x;
    cnt[t] = 0;
    __syncthreads();
    int beg = hoff[b * NBLK];
    int end = (b + 1 < NBUK) ? hoff[(b + 1) * NBLK] : E;
    for (int i = beg + t; i < end; i += 256)
        atomicAdd(&cnt[__builtin_nontemporal_load(scratch + i) >> 20], 1);
    __syncthreads();
    int node = b * BN + t;
    if (node < N) degi[node] = cnt[t];
}

// final CSR fill: one block per bucket, per-node LDS cursors, col writes land
// in a contiguous single-XCD window -> full-line writebacks
__global__ __launch_bounds__(256) void k_scatter2(const unsigned* __restrict__ scratch,
                                                  const int* __restrict__ hoff,
                                                  const int* __restrict__ rowptr,
                                                  int* __restrict__ col,
                                                  int E, int NBUK, int N) {
    __shared__ int cur[BN];
    int b = blockIdx.x;
    int t = threadIdx.x;
    int node = b * BN + t;
    if (node < N) cur[t] = rowptr[node];
    __syncthreads();
    int beg = hoff[b * NBLK];
    int end = (b + 1 < NBUK) ? hoff[(b + 1) * NBLK] : E;
    for (int i = beg + t; i < end; i += 256) {
        unsigned v = __builtin_nontemporal_load(scratch + i);
        int p = atomicAdd(&cur[v >> 20], 1);    // LDS atomic only
        col[p] = (int)(v & 0xFFFFFu);
    }
}

// ---------------------------------------------------------------------------
// bf16 MFMA GEMM (m97 recipe): C[m,n] = A[m,:]·W[n,:], K=256.
// A [N,256] bf16, W [DOUT,256] bf16 (row-major == B^T).
// 128x128 tile, 256 thr = 4 waves (2x2), each wave 4x4 grid of 16x16x32 MFMA.
// Output split: cols [0,DOUTA) -> Y (bf16, ld=DOUTA, temporal: gather source);
//               cols [DOUTA,2*DOUTA) -> R (nt store: read exactly once later).
// ---------------------------------------------------------------------------
template <bool RF32>
__global__ __launch_bounds__(256) void k_gemm_bf16(const unsigned short* __restrict__ A,
                                                   const unsigned short* __restrict__ W,
                                                   unsigned short* __restrict__ Y,
                                                   void* __restrict__ Rv,
                                                   int DOUTA, int N) {
    __shared__ unsigned short As[128 * 32];   // [row][k] bf16, unpadded (global_load_lds)
    __shared__ unsigned short Bs[128 * 32];
    const int tid  = threadIdx.x;
    const int lane = tid & 63;
    const int w    = tid >> 6;
    const int wm   = w & 1, wn = w >> 1;
    const int m0   = blockIdx.x * 128;
    const int n0   = blockIdx.y * 128;
    const int lm   = lane & 15, quad = lane >> 4;

    f32x4 acc[4][4];
#pragma unroll
    for (int i = 0; i < 4; ++i)
#pragma unroll
        for (int j = 0; j < 4; ++j) acc[i][j] = (f32x4){0.f, 0.f, 0.f, 0.f};

    // staging geometry: 8 chunks of 16 rows per tile; wave w stages chunks 2w,2w+1
    const int srow  = lane >> 2;        // row within chunk
    const int skoff = (lane & 3) * 8;   // bf16 offset within 32-wide k slice
    const int ca = 2 * w, cb = 2 * w + 1;

    for (int k0 = 0; k0 < DK; k0 += 32) {
        int ra = min(m0 + 16 * ca + srow, N - 1);   // clamp M tail (stores masked)
        int rb = min(m0 + 16 * cb + srow, N - 1);
        gld_lds16(As + ca * 512, A + (size_t)ra * DK + k0 + skoff);
        gld_lds16(As + cb * 512, A + (size_t)rb * DK + k0 + skoff);
        int na = n0 + 16 * ca + srow;               // DOUT multiple of 128 -> in bounds
        int nb = n0 + 16 * cb + srow;
        gld_lds16(Bs + ca * 512, W + (size_t)na * DK + k0 + skoff);
        gld_lds16(Bs + cb * 512, W + (size_t)nb * DK + k0 + skoff);
        __syncthreads();

        bf16x8 af[4], bfr[4];
#pragma unroll
        for (int mt = 0; mt < 4; ++mt)
            af[mt] = *reinterpret_cast<const bf16x8*>(As + (wm * 64 + mt * 16 + lm) * 32 + quad * 8);
#pragma unroll
        for (int nt = 0; nt < 4; ++nt)
            bfr[nt] = *reinterpret_cast<const bf16x8*>(Bs + (wn * 64 + nt * 16 + lm) * 32 + quad * 8);
#pragma unroll
        for (int mt = 0; mt < 4; ++mt)
#pragma unroll
            for (int nt = 0; nt < 4; ++nt)
                acc[mt][nt] = __builtin_amdgcn_mfma_f32_16x16x32_bf16(af[mt], bfr[nt], acc[mt][nt], 0, 0, 0);
        __syncthreads();
    }

    const bool yPart = (n0 < DOUTA);
#pragma unroll
    for (int mt = 0; mt < 4; ++mt) {
#pragma unroll
        for (int nt = 0; nt < 4; ++nt) {
            int gn = n0 + wn * 64 + nt * 16 + lm;
#pragma unroll
            for (int reg = 0; reg < 4; ++reg) {
                int gm = m0 + wm * 64 + mt * 16 + quad * 4 + reg;
                if (gm < N) {
                    float v = acc[mt][nt][reg];
                    if (yPart) {
                        Y[(size_t)gm * DOUTA + gn] = f2b(v);
                    } else if (RF32) {
                        __builtin_nontemporal_store(
                            v, (float*)Rv + (size_t)gm * DOUTA + (gn - DOUTA));
                    } else {
                        __builtin_nontemporal_store(
                            f2b(v), (unsigned short*)Rv + (size_t)gm * DOUTA + (gn - DOUTA));
                    }
                }
            }
        }
    }
}

// ---------------------------------------------------------------------------
// layer-1 aggregate: H = relu(mean(Y[nbrs]) + bias + R), all feature width 256
// one wave per node; gather loads TEMPORAL (Y resident in L3); everything
// single-use (col, R, H) nontemporal. 4-deep unroll for load ILP.
// ---------------------------------------------------------------------------
__global__ __launch_bounds__(256) void k_agg256(const unsigned short* __restrict__ Y,
                                                const unsigned short* __restrict__ Rb,
                                                const float* __restrict__ bias,
                                                const float* __restrict__ invdeg,
                                                const int* __restrict__ rowptr,
                                                const int* __restrict__ col,
                                                unsigned short* __restrict__ H, int N) {
    long long g = (long long)blockIdx.x * 256 + threadIdx.x;
    int node = (int)(g >> 6);
    int lane = (int)(g & 63);
    if (node >= N) return;
    int beg = rowptr[node], end = rowptr[node + 1];
    const unsigned short* yb = Y + lane * 4;
    float a0 = 0, a1 = 0, a2 = 0, a3 = 0;
    int e = beg;
    for (; e + 3 < end; e += 4) {
        int s0 = __builtin_nontemporal_load(col + e);
        int s1 = __builtin_nontemporal_load(col + e + 1);
        int s2 = __builtin_nontemporal_load(col + e + 2);
        int s3 = __builtin_nontemporal_load(col + e + 3);
        ushort4 v0 = *reinterpret_cast<const ushort4*>(yb + (size_t)s0 * 256);
        ushort4 v1 = *reinterpret_cast<const ushort4*>(yb + (size_t)s1 * 256);
        ushort4 v2 = *reinterpret_cast<const ushort4*>(yb + (size_t)s2 * 256);
        ushort4 v3 = *reinterpret_cast<const ushort4*>(yb + (size_t)s3 * 256);
        a0 += (b2f(v0.x) + b2f(v1.x)) + (b2f(v2.x) + b2f(v3.x));
        a1 += (b2f(v0.y) + b2f(v1.y)) + (b2f(v2.y) + b2f(v3.y));
        a2 += (b2f(v0.z) + b2f(v1.z)) + (b2f(v2.z) + b2f(v3.z));
        a3 += (b2f(v0.w) + b2f(v1.w)) + (b2f(v2.w) + b2f(v3.w));
    }
    for (; e < end; ++e) {
        int s0 = __builtin_nontemporal_load(col + e);
        ushort4 v0 = *reinterpret_cast<const ushort4*>(yb + (size_t)s0 * 256);
        a0 += b2f(v0.x); a1 += b2f(v0.y); a2 += b2f(v0.z); a3 += b2f(v0.w);
    }
    float inv = invdeg[node];
    int c = lane * 4;
    u16x4 r = __builtin_nontemporal_load(
        reinterpret_cast<const u16x4*>(Rb + (size_t)node * 256 + c));
    float o0 = fmaxf(a0 * inv + bias[c + 0] + b2f(r[0]), 0.f);
    float o1 = fmaxf(a1 * inv + bias[c + 1] + b2f(r[1]), 0.f);
    float o2 = fmaxf(a2 * inv + bias[c + 2] + b2f(r[2]), 0.f);
    float o3 = fmaxf(a3 * inv + bias[c + 3] + b2f(r[3]), 0.f);
    u16x4 h = {f2b(o0), f2b(o1), f2b(o2), f2b(o3)};
    __builtin_nontemporal_store(h, reinterpret_cast<u16x4*>(H + (size_t)node * 256 + c));
}

// ---------------------------------------------------------------------------
// layer-2 aggregate: O = mean(Y[nbrs]) + bias + R, width 128, fp32 out
// ---------------------------------------------------------------------------
__global__ __launch_bounds__(256) void k_agg128(const unsigned short* __restrict__ Y,
                                                const float* __restrict__ Rf,
                                                const float* __restrict__ bias,
                                                const float* __restrict__ invdeg,
                                                const int* __restrict__ rowptr,
                                                const int* __restrict__ col,
                                                float* __restrict__ O, int N) {
    long long g = (long long)blockIdx.x * 256 + threadIdx.x;
    int node = (int)(g >> 6);
    int lane = (int)(g & 63);
    if (node >= N) return;
    int beg = rowptr[node], end = rowptr[node + 1];
    const unsigned short* yb = Y + lane * 2;
    float a0 = 0, a1 = 0;
    int e = beg;
    for (; e + 3 < end; e += 4) {
        int s0 = __builtin_nontemporal_load(col + e);
        int s1 = __builtin_nontemporal_load(col + e + 1);
        int s2 = __builtin_nontemporal_load(col + e + 2);
        int s3 = __builtin_nontemporal_load(col + e + 3);
        unsigned v0 = *reinterpret_cast<const unsigned*>(yb + (size_t)s0 * 128);
        unsigned v1 = *reinterpret_cast<const unsigned*>(yb + (size_t)s1 * 128);
        unsigned v2 = *reinterpret_cast<const unsigned*>(yb + (size_t)s2 * 128);
        unsigned v3 = *reinterpret_cast<const unsigned*>(yb + (size_t)s3 * 128);
        a0 += (b2f((unsigned short)(v0 & 0xffff)) + b2f((unsigned short)(v1 & 0xffff)))
            + (b2f((unsigned short)(v2 & 0xffff)) + b2f((unsigned short)(v3 & 0xffff)));
        a1 += (b2f((unsigned short)(v0 >> 16)) + b2f((unsigned short)(v1 >> 16)))
            + (b2f((unsigned short)(v2 >> 16)) + b2f((unsigned short)(v3 >> 16)));
    }
    for (; e < end; ++e) {
        int s0 = __builtin_nontemporal_load(col + e);
        unsigned v0 = *reinterpret_cast<const unsigned*>(yb + (size_t)s0 * 128);
        a0 += b2f((unsigned short)(v0 & 0xffff));
        a1 += b2f((unsigned short)(v0 >> 16));
    }
    float inv = invdeg[node];
    int c = lane * 2;
    f32x2 r = __builtin_nontemporal_load(
        reinterpret_cast<const f32x2*>(Rf + (size_t)node * 128 + c));
    f32x2 o;
    o[0] = a0 * inv + bias[c + 0] + r[0];
    o[1] = a1 * inv + bias[c + 1] + r[1];
    __builtin_nontemporal_store(o, reinterpret_cast<f32x2*>(O + (size_t)node * 128 + c));
}

// ---------------------------------------------------------------------------
extern "C" void kernel_launch(void* const* d_in, const int* in_sizes, int n_in,
                              void* d_out, int out_size, void* d_ws, size_t ws_size,
                              hipStream_t stream) {
    const float* x   = (const float*)d_in[0];
    const int*   ei  = (const int*)d_in[1];
    const float* W1l = (const float*)d_in[2];
    const float* b1  = (const float*)d_in[3];
    const float* W1r = (const float*)d_in[4];
    const float* W2l = (const float*)d_in[5];
    const float* b2  = (const float*)d_in[6];
    const float* W2r = (const float*)d_in[7];
    float* out = (float*)d_out;

    const int N = in_sizes[0] / DK;   // 100000
    const int E = in_sizes[1] / 2;    // 1600000
    const int* src = ei;
    const int* dst = ei + E;

    // workspace (bf16 regions are N*256 elems = 51.2 MB each):
    //   xb | y1b (y2b aliases) | r1b (r2f fp32[N,128] aliases) | hb
    //   Wb1[512*256] Wb2[256*256] | invdeg | degi | rowptr | col | bsum | boff
    // CSR-build temporaries alias dead GEMM buffers:
    //   scratch u32[E] (6.4 MB) -> hb ; hist/hoff/bsum2/boff2 (1.6 MB) -> y1b
    unsigned short* xb  = (unsigned short*)d_ws;
    unsigned short* y1b = xb + (size_t)N * 256;
    unsigned short* r1b = y1b + (size_t)N * 256;
    unsigned short* hb  = r1b + (size_t)N * 256;
    unsigned short* Wb1 = hb + (size_t)N * 256;
    unsigned short* Wb2 = Wb1 + 512 * 256;
    float* invdeg = (float*)(Wb2 + 256 * 256);
    int* degi   = (int*)(invdeg + N);
    int* rowptr = degi + N;
    int* col    = rowptr + (N + 1);
    int* bsum   = col + E;
    int* boff   = bsum + 512;
    unsigned short* y2b = y1b;          // layer-2 aliases (lifetimes disjoint)
    float* r2f = (float*)r1b;

    const int NBUK = (N + BN - 1) / BN;       // 391 buckets
    const int NH   = NBUK * NBLK;             // 200192 histogram entries
    unsigned* scratch = (unsigned*)hb;        // dead before k_agg256 writes hb
    int* hist  = (int*)y1b;                   // dead before layer-1 GEMM
    int* hoff  = hist + NH;
    int* bsum2 = hoff + NH;
    int* boff2 = bsum2 + 512;
    int* tot2  = boff2 + 512;                 // dummy total sink

    // ---- conversions to bf16 ----
    k_cvt<<<(N * 64 + 255) / 256, 256, 0, stream>>>(x, xb, N * 64);
    k_cvt<<<(16384 + 255) / 256, 256, 0, stream>>>(W1l, Wb1, 16384);
    k_cvt<<<(16384 + 255) / 256, 256, 0, stream>>>(W1r, Wb1 + 256 * 256, 16384);
    k_cvt<<<(8192 + 255) / 256, 256, 0, stream>>>(W2l, Wb2, 8192);
    k_cvt<<<(8192 + 255) / 256, 256, 0, stream>>>(W2r, Wb2 + 128 * 256, 8192);

    // ---- CSR build (deterministic counting sort, no global atomics) ----
    const int NB2 = (NH + 1023) / 1024;       // 196 scan blocks for histogram
    const int NB  = (N + 1023) / 1024;        // 98 scan blocks for degrees
    k_hist<<<NBLK, 256, NBUK * sizeof(int), stream>>>(dst, hist, E, NBUK);
    k_scan_a<<<NB2, 256, 0, stream>>>(hist, bsum2, NH);
    k_scan_b<<<1, 256, 0, stream>>>(bsum2, boff2, tot2, NB2);
    k_scan_c2<<<NB2, 256, 0, stream>>>(hist, boff2, hoff, NH);
    k_part<<<NBLK, 256, NBUK * sizeof(int), stream>>>(src, dst, hoff, scratch, E, NBUK);
    k_degb<<<NBUK, 256, 0, stream>>>(scratch, hoff, degi, E, NBUK, N);
    k_scan_a<<<NB, 256, 0, stream>>>(degi, bsum, N);
    k_scan_b<<<1, 256, 0, stream>>>(bsum, boff, rowptr + N, NB);
    k_scan_c<<<NB, 256, 0, stream>>>(degi, boff, rowptr, invdeg, N);
    k_scatter2<<<NBUK, 256, 0, stream>>>(scratch, hoff, rowptr, col, E, NBUK, N);

    int mTiles = (N + 127) / 128;       // 782
    int aggBlocks = (N + 3) / 4;        // 4 nodes (waves) per block

    // ---- layer 1 ----
    k_gemm_bf16<false><<<dim3(mTiles, 4), 256, 0, stream>>>(xb, Wb1, y1b, r1b, 256, N);
    k_agg256<<<aggBlocks, 256, 0, stream>>>(y1b, r1b, b1, invdeg, rowptr, col, hb, N);

    // ---- layer 2 ----
    k_gemm_bf16<true><<<dim3(mTiles, 2), 256, 0, stream>>>(hb, Wb2, y2b, r2f, 128, N);
    k_agg128<<<aggBlocks, 256, 0, stream>>>(y2b, r2f, b2, invdeg, rowptr, col, out, N);
}

// Round 6
// 539.927 us; speedup vs baseline: 1.0796x; 1.0796x over previous
//
#include <hip/hip_runtime.h>

#define DK 256    // K dim of every GEMM (D_IN == D_HID == 256)
#define BN 256    // nodes per CSR bucket (dst >> 8)
#define NBLK 512  // partition blocks for hist/part

typedef __attribute__((ext_vector_type(8))) short bf16x8;   // 8 bf16 in 4 VGPRs
typedef __attribute__((ext_vector_type(4))) float f32x4;

__device__ __forceinline__ unsigned short f2b(float f) {    // RNE fp32->bf16
    unsigned u = __builtin_bit_cast(unsigned, f);
    u += 0x7FFFu + ((u >> 16) & 1u);
    return (unsigned short)(u >> 16);
}
__device__ __forceinline__ float b2f(unsigned short s) {
    return __builtin_bit_cast(float, (unsigned)s << 16);
}
__device__ __forceinline__ void gld_lds16(void* lds, const void* g) {
    __builtin_amdgcn_global_load_lds(
        (const __attribute__((address_space(1))) unsigned int*)g,
        (__attribute__((address_space(3))) unsigned int*)lds, 16, 0, 0);
}

// ---------------------------------------------------------------------------
// fp32 -> bf16 conversion, 4 elems/thread
// ---------------------------------------------------------------------------
__global__ __launch_bounds__(256) void k_cvt(const float* __restrict__ src,
                                             unsigned short* __restrict__ dst, int n4) {
    int i = blockIdx.x * 256 + threadIdx.x;
    if (i < n4) {
        float4 v = reinterpret_cast<const float4*>(src)[i];
        ushort4 o = make_ushort4(f2b(v.x), f2b(v.y), f2b(v.z), f2b(v.w));
        reinterpret_cast<ushort4*>(dst)[i] = o;
    }
}

// ---------------------------------------------------------------------------
// generic 3-kernel exclusive scan (1024 elems per scan_a/scan_c block)
// ---------------------------------------------------------------------------
__global__ __launch_bounds__(256) void k_scan_a(const int* __restrict__ in,
                                                int* __restrict__ bsum, int N) {
    __shared__ int sm[256];
    int t = threadIdx.x;
    int i0 = blockIdx.x * 1024 + t * 4;
    int s = 0;
    if (i0 + 3 < N) {
        int4 v = *reinterpret_cast<const int4*>(in + i0);
        s = v.x + v.y + v.z + v.w;
    } else {
        for (int i = i0; i < min(i0 + 4, N); ++i) s += in[i];
    }
    sm[t] = s;
    __syncthreads();
    for (int off = 128; off > 0; off >>= 1) {
        if (t < off) sm[t] += sm[t + off];
        __syncthreads();
    }
    if (t == 0) bsum[blockIdx.x] = sm[0];
}

__global__ __launch_bounds__(256) void k_scan_b(const int* __restrict__ bsum,
                                                int* __restrict__ boff,
                                                int* __restrict__ totN, int NB) {
    __shared__ int sm[256];
    int t = threadIdx.x;
    sm[t] = (t < NB) ? bsum[t] : 0;
    __syncthreads();
    for (int off = 1; off < 256; off <<= 1) {
        int v = (t >= off) ? sm[t - off] : 0;
        __syncthreads();
        sm[t] += v;
        __syncthreads();
    }
    if (t < NB) boff[t] = (t == 0) ? 0 : sm[t - 1];
    if (t == NB - 1) *totN = sm[t];
}

// exclusive-scan writeback + rowptr/invdeg epilogue (for degi scan)
__global__ __launch_bounds__(256) void k_scan_c(const int* __restrict__ in,
                                                const int* __restrict__ boff,
                                                int* __restrict__ rowptr,
                                                float* __restrict__ invdeg, int N) {
    __shared__ int sm[256];
    int t = threadIdx.x;
    int i0 = blockIdx.x * 1024 + t * 4;
    int d0 = 0, d1 = 0, d2 = 0, d3 = 0;
    if (i0 + 3 < N) {
        int4 v = *reinterpret_cast<const int4*>(in + i0);
        d0 = v.x; d1 = v.y; d2 = v.z; d3 = v.w;
    } else {
        if (i0 + 0 < N) d0 = in[i0 + 0];
        if (i0 + 1 < N) d1 = in[i0 + 1];
        if (i0 + 2 < N) d2 = in[i0 + 2];
        if (i0 + 3 < N) d3 = in[i0 + 3];
    }
    int s = d0 + d1 + d2 + d3;
    sm[t] = s;
    __syncthreads();
    for (int off = 1; off < 256; off <<= 1) {
        int v = (t >= off) ? sm[t - off] : 0;
        __syncthreads();
        sm[t] += v;
        __syncthreads();
    }
    int run = boff[blockIdx.x] + sm[t] - s;    // exclusive prefix of this thread
    int dd[4] = {d0, d1, d2, d3};
#pragma unroll
    for (int i = 0; i < 4; ++i) {
        int idx = i0 + i;
        if (idx < N) {
            rowptr[idx] = run;
            invdeg[idx] = 1.0f / fmaxf((float)dd[i], 1.0f);
            run += dd[i];
        }
    }
}

// exclusive-scan writeback, plain (for histogram scan)
__global__ __launch_bounds__(256) void k_scan_c2(const int* __restrict__ in,
                                                 const int* __restrict__ boff,
                                                 int* __restrict__ outx, int N) {
    __shared__ int sm[256];
    int t = threadIdx.x;
    int i0 = blockIdx.x * 1024 + t * 4;
    int d0 = 0, d1 = 0, d2 = 0, d3 = 0;
    if (i0 + 3 < N) {
        int4 v = *reinterpret_cast<const int4*>(in + i0);
        d0 = v.x; d1 = v.y; d2 = v.z; d3 = v.w;
    } else {
        if (i0 + 0 < N) d0 = in[i0 + 0];
        if (i0 + 1 < N) d1 = in[i0 + 1];
        if (i0 + 2 < N) d2 = in[i0 + 2];
        if (i0 + 3 < N) d3 = in[i0 + 3];
    }
    int s = d0 + d1 + d2 + d3;
    sm[t] = s;
    __syncthreads();
    for (int off = 1; off < 256; off <<= 1) {
        int v = (t >= off) ? sm[t - off] : 0;
        __syncthreads();
        sm[t] += v;
        __syncthreads();
    }
    int run = boff[blockIdx.x] + sm[t] - s;
    int dd[4] = {d0, d1, d2, d3};
#pragma unroll
    for (int i = 0; i < 4; ++i) {
        int idx = i0 + i;
        if (idx < N) { outx[idx] = run; run += dd[i]; }
    }
}

// ---------------------------------------------------------------------------
// CSR build via deterministic counting-sort partition (no global atomics)
// ---------------------------------------------------------------------------
// pass A: per-block LDS histogram over NBUK buckets of dst>>8
__global__ __launch_bounds__(256) void k_hist(const int* __restrict__ dst,
                                              int* __restrict__ hist,
                                              int E, int NBUK) {
    extern __shared__ int h[];
    int t = threadIdx.x;
    for (int b = t; b < NBUK; b += 256) h[b] = 0;
    __syncthreads();
    int CH = (E + NBLK - 1) / NBLK;
    int beg = blockIdx.x * CH;
    int end = min(beg + CH, E);
    for (int i = beg + t; i < end; i += 256)
        atomicAdd(&h[dst[i] >> 8], 1);
    __syncthreads();
    for (int b = t; b < NBUK; b += 256)
        hist[b * NBLK + blockIdx.x] = h[b];     // bucket-major for the scan
}

// pass B: deterministic placement; pack src | (dst&255)<<20 into 4B
__global__ __launch_bounds__(256) void k_part(const int* __restrict__ src,
                                              const int* __restrict__ dst,
                                              const int* __restrict__ hoff,
                                              unsigned* __restrict__ scratch,
                                              int E, int NBUK) {
    extern __shared__ int cur[];
    int t = threadIdx.x;
    for (int b = t; b < NBUK; b += 256) cur[b] = hoff[b * NBLK + blockIdx.x];
    __syncthreads();
    int CH = (E + NBLK - 1) / NBLK;
    int beg = blockIdx.x * CH;
    int end = min(beg + CH, E);
    for (int i = beg + t; i < end; i += 256) {
        int d = dst[i];
        int p = atomicAdd(&cur[d >> 8], 1);     // LDS atomic only
        scratch[p] = (unsigned)src[i] | ((unsigned)(d & 255) << 20);
    }
}

// per-bucket degree count from sorted scratch (replaces global-atomic k_deg_i)
__global__ __launch_bounds__(256) void k_degb(const unsigned* __restrict__ scratch,
                                              const int* __restrict__ hoff,
                                              int* __restrict__ degi,
                                              int E, int NBUK, int N) {
    __shared__ int cnt[BN];
    int b = blockIdx.x;
    int t = threadIdx.x;
    cnt[t] = 0;
    __syncthreads();
    int beg = hoff[b * NBLK];
    int end = (b + 1 < NBUK) ? hoff[(b + 1) * NBLK] : E;
    for (int i = beg + t; i < end; i += 256)
        atomicAdd(&cnt[scratch[i] >> 20], 1);
    __syncthreads();
    int node = b * BN + t;
    if (node < N) degi[node] = cnt[t];
}

// final CSR fill: one block per bucket, per-node LDS cursors, col writes land
// in a contiguous single-XCD window -> full-line writebacks
__global__ __launch_bounds__(256) void k_scatter2(const unsigned* __restrict__ scratch,
                                                  const int* __restrict__ hoff,
                                                  const int* __restrict__ rowptr,
                                                  int* __restrict__ col,
                                                  int E, int NBUK, int N) {
    __shared__ int cur[BN];
    int b = blockIdx.x;
    int t = threadIdx.x;
    int node = b * BN + t;
    if (node < N) cur[t] = rowptr[node];
    __syncthreads();
    int beg = hoff[b * NBLK];
    int end = (b + 1 < NBUK) ? hoff[(b + 1) * NBLK] : E;
    for (int i = beg + t; i < end; i += 256) {
        unsigned v = scratch[i];
        int p = atomicAdd(&cur[v >> 20], 1);    // LDS atomic only
        col[p] = (int)(v & 0xFFFFFu);
    }
}

// ---------------------------------------------------------------------------
// bf16 MFMA GEMM (m97 recipe): C[m,n] = A[m,:]·W[n,:], K=256.
// A [N,256] bf16, W [DOUT,256] bf16 (row-major == B^T).
// 128x128 tile, 256 thr = 4 waves (2x2), each wave 4x4 grid of 16x16x32 MFMA.
// Output split: cols [0,DOUTA) -> Y (bf16, ld=DOUTA);
//               cols [DOUTA,2*DOUTA) -> R (bf16 or fp32 per RF32, ld=DOUTA).
// Bias/relu live in the aggregation kernels.
// ---------------------------------------------------------------------------
template <bool RF32>
__global__ __launch_bounds__(256) void k_gemm_bf16(const unsigned short* __restrict__ A,
                                                   const unsigned short* __restrict__ W,
                                                   unsigned short* __restrict__ Y,
                                                   void* __restrict__ Rv,
                                                   int DOUTA, int N) {
    __shared__ unsigned short As[128 * 32];   // [row][k] bf16, unpadded (global_load_lds)
    __shared__ unsigned short Bs[128 * 32];
    const int tid  = threadIdx.x;
    const int lane = tid & 63;
    const int w    = tid >> 6;
    const int wm   = w & 1, wn = w >> 1;
    const int m0   = blockIdx.x * 128;
    const int n0   = blockIdx.y * 128;
    const int lm   = lane & 15, quad = lane >> 4;

    f32x4 acc[4][4];
#pragma unroll
    for (int i = 0; i < 4; ++i)
#pragma unroll
        for (int j = 0; j < 4; ++j) acc[i][j] = (f32x4){0.f, 0.f, 0.f, 0.f};

    // staging geometry: 8 chunks of 16 rows per tile; wave w stages chunks 2w,2w+1
    const int srow  = lane >> 2;        // row within chunk
    const int skoff = (lane & 3) * 8;   // bf16 offset within 32-wide k slice
    const int ca = 2 * w, cb = 2 * w + 1;

    for (int k0 = 0; k0 < DK; k0 += 32) {
        int ra = min(m0 + 16 * ca + srow, N - 1);   // clamp M tail (stores masked)
        int rb = min(m0 + 16 * cb + srow, N - 1);
        gld_lds16(As + ca * 512, A + (size_t)ra * DK + k0 + skoff);
        gld_lds16(As + cb * 512, A + (size_t)rb * DK + k0 + skoff);
        int na = n0 + 16 * ca + srow;               // DOUT multiple of 128 -> in bounds
        int nb = n0 + 16 * cb + srow;
        gld_lds16(Bs + ca * 512, W + (size_t)na * DK + k0 + skoff);
        gld_lds16(Bs + cb * 512, W + (size_t)nb * DK + k0 + skoff);
        __syncthreads();

        bf16x8 af[4], bfr[4];
#pragma unroll
        for (int mt = 0; mt < 4; ++mt)
            af[mt] = *reinterpret_cast<const bf16x8*>(As + (wm * 64 + mt * 16 + lm) * 32 + quad * 8);
#pragma unroll
        for (int nt = 0; nt < 4; ++nt)
            bfr[nt] = *reinterpret_cast<const bf16x8*>(Bs + (wn * 64 + nt * 16 + lm) * 32 + quad * 8);
#pragma unroll
        for (int mt = 0; mt < 4; ++mt)
#pragma unroll
            for (int nt = 0; nt < 4; ++nt)
                acc[mt][nt] = __builtin_amdgcn_mfma_f32_16x16x32_bf16(af[mt], bfr[nt], acc[mt][nt], 0, 0, 0);
        __syncthreads();
    }

    const bool yPart = (n0 < DOUTA);
#pragma unroll
    for (int mt = 0; mt < 4; ++mt) {
#pragma unroll
        for (int nt = 0; nt < 4; ++nt) {
            int gn = n0 + wn * 64 + nt * 16 + lm;
#pragma unroll
            for (int reg = 0; reg < 4; ++reg) {
                int gm = m0 + wm * 64 + mt * 16 + quad * 4 + reg;
                if (gm < N) {
                    float v = acc[mt][nt][reg];
                    if (yPart) {
                        Y[(size_t)gm * DOUTA + gn] = f2b(v);
                    } else if (RF32) {
                        ((float*)Rv)[(size_t)gm * DOUTA + (gn - DOUTA)] = v;
                    } else {
                        ((unsigned short*)Rv)[(size_t)gm * DOUTA + (gn - DOUTA)] = f2b(v);
                    }
                }
            }
        }
    }
}

// ---------------------------------------------------------------------------
// layer-1 aggregate: H = relu(mean(Y[nbrs]) + bias + R), all feature width 256
// one wave per node, lane holds 4 features (8B loads), fp32 accumulate.
// 8-deep unrolled gather: 8 independent row loads in flight per wave (MLP).
// ---------------------------------------------------------------------------
__global__ __launch_bounds__(256) void k_agg256(const unsigned short* __restrict__ Y,
                                                const unsigned short* __restrict__ Rb,
                                                const float* __restrict__ bias,
                                                const float* __restrict__ invdeg,
                                                const int* __restrict__ rowptr,
                                                const int* __restrict__ col,
                                                unsigned short* __restrict__ H, int N) {
    long long g = (long long)blockIdx.x * 256 + threadIdx.x;
    int node = (int)(g >> 6);
    int lane = (int)(g & 63);
    if (node >= N) return;
    int beg = rowptr[node], end = rowptr[node + 1];
    const unsigned short* yb = Y + lane * 4;
    float a0 = 0, a1 = 0, a2 = 0, a3 = 0;
    int e = beg;
    for (; e + 7 < end; e += 8) {
        int s[8];
#pragma unroll
        for (int u = 0; u < 8; ++u) s[u] = col[e + u];
        ushort4 v[8];
#pragma unroll
        for (int u = 0; u < 8; ++u)
            v[u] = *reinterpret_cast<const ushort4*>(yb + (size_t)s[u] * 256);
#pragma unroll
        for (int u = 0; u < 8; ++u) {
            a0 += b2f(v[u].x);
            a1 += b2f(v[u].y);
            a2 += b2f(v[u].z);
            a3 += b2f(v[u].w);
        }
    }
    for (; e < end; ++e) {
        ushort4 v0 = *reinterpret_cast<const ushort4*>(yb + (size_t)col[e] * 256);
        a0 += b2f(v0.x); a1 += b2f(v0.y); a2 += b2f(v0.z); a3 += b2f(v0.w);
    }
    float inv = invdeg[node];
    int c = lane * 4;
    ushort4 r = *reinterpret_cast<const ushort4*>(Rb + (size_t)node * 256 + c);
    float o0 = fmaxf(a0 * inv + bias[c + 0] + b2f(r.x), 0.f);
    float o1 = fmaxf(a1 * inv + bias[c + 1] + b2f(r.y), 0.f);
    float o2 = fmaxf(a2 * inv + bias[c + 2] + b2f(r.z), 0.f);
    float o3 = fmaxf(a3 * inv + bias[c + 3] + b2f(r.w), 0.f);
    *reinterpret_cast<ushort4*>(H + (size_t)node * 256 + c) =
        make_ushort4(f2b(o0), f2b(o1), f2b(o2), f2b(o3));
}

// ---------------------------------------------------------------------------
// layer-2 aggregate: O = mean(Y[nbrs]) + bias + R, width 128, fp32 out
// 8-deep unrolled gather for MLP.
// ---------------------------------------------------------------------------
__global__ __launch_bounds__(256) void k_agg128(const unsigned short* __restrict__ Y,
                                                const float* __restrict__ Rf,
                                                const float* __restrict__ bias,
                                                const float* __restrict__ invdeg,
                                                const int* __restrict__ rowptr,
                                                const int* __restrict__ col,
                                                float* __restrict__ O, int N) {
    long long g = (long long)blockIdx.x * 256 + threadIdx.x;
    int node = (int)(g >> 6);
    int lane = (int)(g & 63);
    if (node >= N) return;
    int beg = rowptr[node], end = rowptr[node + 1];
    const unsigned short* yb = Y + lane * 2;
    float a0 = 0, a1 = 0;
    int e = beg;
    for (; e + 7 < end; e += 8) {
        int s[8];
#pragma unroll
        for (int u = 0; u < 8; ++u) s[u] = col[e + u];
        unsigned v[8];
#pragma unroll
        for (int u = 0; u < 8; ++u)
            v[u] = *reinterpret_cast<const unsigned*>(yb + (size_t)s[u] * 128);
#pragma unroll
        for (int u = 0; u < 8; ++u) {
            a0 += b2f((unsigned short)(v[u] & 0xffff));
            a1 += b2f((unsigned short)(v[u] >> 16));
        }
    }
    for (; e < end; ++e) {
        unsigned v0 = *reinterpret_cast<const unsigned*>(yb + (size_t)col[e] * 128);
        a0 += b2f((unsigned short)(v0 & 0xffff));
        a1 += b2f((unsigned short)(v0 >> 16));
    }
    float inv = invdeg[node];
    int c = lane * 2;
    float2 r = *reinterpret_cast<const float2*>(Rf + (size_t)node * 128 + c);
    float2 o;
    o.x = a0 * inv + bias[c + 0] + r.x;
    o.y = a1 * inv + bias[c + 1] + r.y;
    *reinterpret_cast<float2*>(O + (size_t)node * 128 + c) = o;
}

// ---------------------------------------------------------------------------
extern "C" void kernel_launch(void* const* d_in, const int* in_sizes, int n_in,
                              void* d_out, int out_size, void* d_ws, size_t ws_size,
                              hipStream_t stream) {
    const float* x   = (const float*)d_in[0];
    const int*   ei  = (const int*)d_in[1];
    const float* W1l = (const float*)d_in[2];
    const float* b1  = (const float*)d_in[3];
    const float* W1r = (const float*)d_in[4];
    const float* W2l = (const float*)d_in[5];
    const float* b2  = (const float*)d_in[6];
    const float* W2r = (const float*)d_in[7];
    float* out = (float*)d_out;

    const int N = in_sizes[0] / DK;   // 100000
    const int E = in_sizes[1] / 2;    // 1600000
    const int* src = ei;
    const int* dst = ei + E;

    // workspace (bf16 regions are N*256 elems = 51.2 MB each):
    //   xb | y1b (y2b aliases) | r1b (r2f fp32[N,128] aliases) | hb
    //   Wb1[512*256] Wb2[256*256] | invdeg | degi | rowptr | col | bsum | boff
    // CSR-build temporaries alias dead GEMM buffers:
    //   scratch u32[E] (6.4 MB) -> hb ; hist/hoff/bsum2/boff2 (1.6 MB) -> y1b
    unsigned short* xb  = (unsigned short*)d_ws;
    unsigned short* y1b = xb + (size_t)N * 256;
    unsigned short* r1b = y1b + (size_t)N * 256;
    unsigned short* hb  = r1b + (size_t)N * 256;
    unsigned short* Wb1 = hb + (size_t)N * 256;
    unsigned short* Wb2 = Wb1 + 512 * 256;
    float* invdeg = (float*)(Wb2 + 256 * 256);
    int* degi   = (int*)(invdeg + N);
    int* rowptr = degi + N;
    int* col    = rowptr + (N + 1);
    int* bsum   = col + E;
    int* boff   = bsum + 512;
    unsigned short* y2b = y1b;          // layer-2 aliases (lifetimes disjoint)
    float* r2f = (float*)r1b;

    const int NBUK = (N + BN - 1) / BN;       // 391 buckets
    const int NH   = NBUK * NBLK;             // 200192 histogram entries
    unsigned* scratch = (unsigned*)hb;        // dead before k_agg256 writes hb
    int* hist  = (int*)y1b;                   // dead before layer-1 GEMM
    int* hoff  = hist + NH;
    int* bsum2 = hoff + NH;
    int* boff2 = bsum2 + 512;
    int* tot2  = boff2 + 512;                 // dummy total sink

    // ---- conversions to bf16 ----
    k_cvt<<<(N * 64 + 255) / 256, 256, 0, stream>>>(x, xb, N * 64);
    k_cvt<<<(16384 + 255) / 256, 256, 0, stream>>>(W1l, Wb1, 16384);
    k_cvt<<<(16384 + 255) / 256, 256, 0, stream>>>(W1r, Wb1 + 256 * 256, 16384);
    k_cvt<<<(8192 + 255) / 256, 256, 0, stream>>>(W2l, Wb2, 8192);
    k_cvt<<<(8192 + 255) / 256, 256, 0, stream>>>(W2r, Wb2 + 128 * 256, 8192);

    // ---- CSR build (deterministic counting sort, no global atomics) ----
    const int NB2 = (NH + 1023) / 1024;       // 196 scan blocks for histogram
    const int NB  = (N + 1023) / 1024;        // 98 scan blocks for degrees
    k_hist<<<NBLK, 256, NBUK * sizeof(int), stream>>>(dst, hist, E, NBUK);
    k_scan_a<<<NB2, 256, 0, stream>>>(hist, bsum2, NH);
    k_scan_b<<<1, 256, 0, stream>>>(bsum2, boff2, tot2, NB2);
    k_scan_c2<<<NB2, 256, 0, stream>>>(hist, boff2, hoff, NH);
    k_part<<<NBLK, 256, NBUK * sizeof(int), stream>>>(src, dst, hoff, scratch, E, NBUK);
    k_degb<<<NBUK, 256, 0, stream>>>(scratch, hoff, degi, E, NBUK, N);
    k_scan_a<<<NB, 256, 0, stream>>>(degi, bsum, N);
    k_scan_b<<<1, 256, 0, stream>>>(bsum, boff, rowptr + N, NB);
    k_scan_c<<<NB, 256, 0, stream>>>(degi, boff, rowptr, invdeg, N);
    k_scatter2<<<NBUK, 256, 0, stream>>>(scratch, hoff, rowptr, col, E, NBUK, N);

    int mTiles = (N + 127) / 128;       // 782
    int aggBlocks = (N + 3) / 4;        // 4 nodes (waves) per block

    // ---- layer 1 ----
    k_gemm_bf16<false><<<dim3(mTiles, 4), 256, 0, stream>>>(xb, Wb1, y1b, r1b, 256, N);
    k_agg256<<<aggBlocks, 256, 0, stream>>>(y1b, r1b, b1, invdeg, rowptr, col, hb, N);

    // ---- layer 2 ----
    k_gemm_bf16<true><<<dim3(mTiles, 2), 256, 0, stream>>>(hb, Wb2, y2b, r2f, 128, N);
    k_agg128<<<aggBlocks, 256, 0, stream>>>(y2b, r2f, b2, invdeg, rowptr, col, out, N);
}